// Round 1
// 418.806 us; speedup vs baseline: 1.0401x; 1.0401x over previous
//
#include <hip/hip_runtime.h>
#include <math.h>

// HydraAttention R5 — conv3x3 re-expressed as implicit GEMM (m97 structure).
//
// R4's conv3x3_mfma was latency-bound: 62 KB LDS staged per 32-ch chunk behind
// a full vmcnt(0)+barrier drain, 2 blocks/CU, MfmaUtil 17%, 5.8M bank-conflict
// cycles. R5 replaces it with conv_gemm: K = 2304 (9 taps x 256 ch), A = folded
// weights [m][d*256+c] (layout already produced by prep1/gemm), B = im2col
// gather of the image with chunk-uniform tap shift (256%32==0 so each 32-wide
// K-chunk sits inside one tap). 128x128 tile, 16 KB LDS/K-step, proven
// 2-barrier structure (~37% MfmaUtil on this shape). Border granules zeroed
// via direct LDS store (same OOB idiom as R4).

typedef unsigned short u16;
typedef __attribute__((ext_vector_type(8))) short short8;
typedef __attribute__((ext_vector_type(4))) float f32x4;
typedef __attribute__((ext_vector_type(4))) unsigned short us4v;

#define ASYNC16(g, l) __builtin_amdgcn_global_load_lds( \
    (const __attribute__((address_space(1))) unsigned int*)(g), \
    (__attribute__((address_space(3))) unsigned int*)(l), 16, 0, 0)

static __device__ __forceinline__ float b2f(u16 h) {
  unsigned int u = ((unsigned int)h) << 16;
  return __builtin_bit_cast(float, u);
}
static __device__ __forceinline__ u16 f2b(float f) {
  unsigned int u = __builtin_bit_cast(unsigned int, f);
  u += 0x7fffu + ((u >> 16) & 1u);
  return (u16)(u >> 16);
}

#define NB 1048576L

// ---------------- prep1: weight converts/reorders + kvbias ----------------
__global__ __launch_bounds__(256) void prep1(
    const float* __restrict__ qw, const float* __restrict__ kw,
    const float* __restrict__ vw, const float* __restrict__ rw,
    const float* __restrict__ c1w, const float* __restrict__ c2w,
    const float* __restrict__ kb, const float* __restrict__ vb,
    u16* __restrict__ qw16, u16* __restrict__ kvw16, u16* __restrict__ rwT16,
    u16* __restrict__ wr1, u16* __restrict__ wr2,
    float* __restrict__ kvbias)
{
  if (blockIdx.x == 5632) {
    int t = threadIdx.x;
    if (t < 512) kvbias[t] = (t < 256) ? kb[t] : vb[t - 256];
    return;
  }
  long g = (long)blockIdx.x * 256 + threadIdx.x;
  if (g < 65536) {
    qw16[g] = f2b(qw[g]);
  } else if (g < 196608) {
    long e = g - 65536;
    kvw16[e] = f2b(e < 65536 ? kw[e] : vw[e - 65536]);
  } else if (g < 262144) {
    long e = g - 196608;
    int cv = e >> 8, co = e & 255;
    rwT16[e] = f2b(rw[co * 256 + cv]);
  } else if (g < 851968) {
    long e = g - 262144;
    int m = e / 2304, r = e - m * 2304;
    int d = r >> 8, c = r & 255;
    wr1[e] = f2b(c1w[m * 2304 + c * 9 + d]);
  } else {
    long e = g - 851968;
    int m = e / 2304, r = e - m * 2304;
    int d = r >> 8, c = r & 255;
    wr2[e] = f2b(c2w[m * 2304 + c * 9 + d]);
  }
}

// T[m*9+t] = sum_co c1w[m][co][t]*rb[co]
__global__ __launch_bounds__(256) void prep_T(
    const float* __restrict__ c1w, const float* __restrict__ rb, float* __restrict__ T)
{
  int e = blockIdx.x * 256 + threadIdx.x;   // 2304
  int m = e / 9, d = e - m * 9;
  float s = 0.f;
  for (int co = 0; co < 256; co++) s += c1w[m * 2304 + co * 9 + d] * rb[co];
  T[e] = s;
}

// corr[m][p] = c1b[m] + sum_{t valid at p} T[m][t]
__global__ __launch_bounds__(256) void corr_k(
    const float* __restrict__ T, const float* __restrict__ c1b, float* __restrict__ corr)
{
  int e = blockIdx.x * 256 + threadIdx.x;   // 1048576
  int m = e >> 12, p = e & 4095;
  int y = p >> 6, xx = p & 63;
  float s = c1b[m];
#pragma unroll
  for (int d = 0; d < 9; d++) {
    int dy = d / 3 - 1, dx = d - (d / 3) * 3 - 1;
    if ((unsigned)(y + dy) < 64u && (unsigned)(xx + dx) < 64u) s += T[m * 9 + d];
  }
  corr[e] = s;
}

// ---------------- x [b][c][n] f32 -> xT16 [b][n][c] bf16 ----------------
__global__ __launch_bounds__(256) void transposeX(
    const float* __restrict__ x, u16* __restrict__ xT)
{
  __shared__ float T[64][65];
  int n0 = blockIdx.x * 64, c0 = blockIdx.y * 64, b = blockIdx.z;
  int t = threadIdx.x;
#pragma unroll
  for (int i = 0; i < 4; i++) {
    int c = (t >> 4) + i * 16, nn = (t & 15) * 4;
    float4 v = *(const float4*)&x[(long)b * NB + (long)(c0 + c) * 4096 + n0 + nn];
    T[c][nn] = v.x; T[c][nn + 1] = v.y; T[c][nn + 2] = v.z; T[c][nn + 3] = v.w;
  }
  __syncthreads();
#pragma unroll
  for (int i = 0; i < 4; i++) {
    int n = (t >> 4) + i * 16, cc = (t & 15) * 4;
    us4v o;
#pragma unroll
    for (int e = 0; e < 4; e++) o[e] = f2b(T[cc + e][n]);
    *(us4v*)&xT[(long)b * NB + (long)(n0 + n) * 256 + c0 + cc] = o;
  }
}

// ---------------- generic NT bf16 MFMA GEMM (global_load_lds staging) ----------------
// D[i][j] = sum_k A[i][k]*B[j][k]
// mode 0: v += (p1?p1[row]:0) + (p2?p2[col]:0)
// mode 2: v = (v + p1[b*256+col]) * p2[b*4096+row]
__global__ __launch_bounds__(256) void gemm_nt(
    const u16* __restrict__ A, const u16* __restrict__ B, u16* __restrict__ out,
    int K, int lda, int ldb, long sAb, long sBb, long sOb, long sR, long sC,
    int mode, const float* __restrict__ p1, const float* __restrict__ p2)
{
  __shared__ __align__(16) u16 As[128 * 32];
  __shared__ __align__(16) u16 Bs[128 * 32];
  int b = blockIdx.z;
  long i0 = (long)blockIdx.y * 128;
  long j0 = (long)blockIdx.x * 128;
  const u16* Ab = A + b * sAb + i0 * lda;
  const u16* Bb = B + b * sBb + j0 * ldb;
  int t = threadIdx.x, wave = t >> 6, lane = t & 63;
  int wi = (wave >> 1) * 64, wj = (wave & 1) * 64;
  int li = lane & 15, quad = lane >> 4;
  f32x4 acc[4][4];
#pragma unroll
  for (int i = 0; i < 4; i++)
#pragma unroll
    for (int j = 0; j < 4; j++) acc[i][j] = (f32x4){0.f, 0.f, 0.f, 0.f};

  for (int k0 = 0; k0 < K; k0 += 32) {
#pragma unroll
    for (int h = 0; h < 2; h++) {
      int chunk = wave * 128 + h * 64 + lane;
      int r = chunk >> 2, q = chunk & 3;
      ASYNC16(Ab + (long)r * lda + k0 + q * 8, &As[(wave * 128 + h * 64) * 8]);
      ASYNC16(Bb + (long)r * ldb + k0 + q * 8, &Bs[(wave * 128 + h * 64) * 8]);
    }
    __syncthreads();
    short8 af[4], bf[4];
#pragma unroll
    for (int s = 0; s < 4; s++) af[s] = *(const short8*)&As[(wi + s * 16 + li) * 32 + quad * 8];
#pragma unroll
    for (int s = 0; s < 4; s++) bf[s] = *(const short8*)&Bs[(wj + s * 16 + li) * 32 + quad * 8];
#pragma unroll
    for (int si = 0; si < 4; si++)
#pragma unroll
      for (int sj = 0; sj < 4; sj++)
        acc[si][sj] = __builtin_amdgcn_mfma_f32_16x16x32_bf16(af[si], bf[sj], acc[si][sj], 0, 0, 0);
    __syncthreads();
  }

#pragma unroll
  for (int si = 0; si < 4; si++)
#pragma unroll
    for (int sj = 0; sj < 4; sj++) {
      long col = j0 + wj + sj * 16 + li;
#pragma unroll
      for (int r = 0; r < 4; r++) {
        long row = i0 + wi + si * 16 + quad * 4 + r;
        float v = acc[si][sj][r];
        if (mode == 0) {
          if (p1) v += p1[row];
          if (p2) v += p2[col];
        } else {
          v = (v + p1[b * 256 + col]) * p2[b * 4096 + row];
        }
        out[b * sOb + row * sR + col * sC] = f2b(v);
      }
    }
}

// ---------------- kv split-n GEMM: part[sp][b][cv][ck] f32 ----------------
__global__ __launch_bounds__(256) void gemm_kv(
    const u16* __restrict__ KV, float* __restrict__ part)
{
  __shared__ __align__(16) u16 As[128 * 32];
  __shared__ __align__(16) u16 Bs[128 * 32];
  int z = blockIdx.z;
  int b = z & 7, sp = z >> 3;
  long i0 = (long)blockIdx.y * 128;   // ck
  long j0 = (long)blockIdx.x * 128;   // cv
  const u16* Ab = KV + (long)b * 2 * NB + i0 * 4096;        // K rows
  const u16* Bb = KV + (long)b * 2 * NB + NB + j0 * 4096;   // V rows
  int t = threadIdx.x, wave = t >> 6, lane = t & 63;
  int wi = (wave >> 1) * 64, wj = (wave & 1) * 64;
  int li = lane & 15, quad = lane >> 4;
  f32x4 acc[4][4];
#pragma unroll
  for (int i = 0; i < 4; i++)
#pragma unroll
    for (int j = 0; j < 4; j++) acc[i][j] = (f32x4){0.f, 0.f, 0.f, 0.f};

  int kend = sp * 512 + 512;
  for (int k0 = sp * 512; k0 < kend; k0 += 32) {
#pragma unroll
    for (int h = 0; h < 2; h++) {
      int chunk = wave * 128 + h * 64 + lane;
      int r = chunk >> 2, q = chunk & 3;
      ASYNC16(Ab + (long)r * 4096 + k0 + q * 8, &As[(wave * 128 + h * 64) * 8]);
      ASYNC16(Bb + (long)r * 4096 + k0 + q * 8, &Bs[(wave * 128 + h * 64) * 8]);
    }
    __syncthreads();
    short8 af[4], bf[4];
#pragma unroll
    for (int s = 0; s < 4; s++) af[s] = *(const short8*)&As[(wi + s * 16 + li) * 32 + quad * 8];
#pragma unroll
    for (int s = 0; s < 4; s++) bf[s] = *(const short8*)&Bs[(wj + s * 16 + li) * 32 + quad * 8];
#pragma unroll
    for (int si = 0; si < 4; si++)
#pragma unroll
      for (int sj = 0; sj < 4; sj++)
        acc[si][sj] = __builtin_amdgcn_mfma_f32_16x16x32_bf16(af[si], bf[sj], acc[si][sj], 0, 0, 0);
    __syncthreads();
  }

  float* outp = part + ((long)sp * 8 + b) * 65536;
#pragma unroll
  for (int si = 0; si < 4; si++)
#pragma unroll
    for (int sj = 0; sj < 4; sj++) {
      long col = j0 + wj + sj * 16 + li;   // cv
#pragma unroll
      for (int r = 0; r < 4; r++) {
        long row = i0 + wi + si * 16 + quad * 4 + r;  // ck
        outp[col * 256 + row] = acc[si][sj][r];
      }
    }
}

__global__ __launch_bounds__(256) void reduce_kv(
    const float* __restrict__ part, u16* __restrict__ kvT)
{
  int g = blockIdx.x * 256 + threadIdx.x;  // 524288
  float s = 0.f;
#pragma unroll
  for (int sp = 0; sp < 8; sp++) s += part[(long)sp * 524288 + g];
  kvT[g] = f2b(s);
}

// ---------------- normalize Qt rows ----------------
__global__ __launch_bounds__(256) void normQ(u16* __restrict__ Qt)
{
  int row = blockIdx.x * 4 + (threadIdx.x >> 6);
  int lane = threadIdx.x & 63;
  u16* p = Qt + (long)row * 256 + lane * 4;
  us4v v = *(const us4v*)p;
  float f0 = b2f(v[0]), f1 = b2f(v[1]), f2 = b2f(v[2]), f3 = b2f(v[3]);
  float s = f0 * f0 + f1 * f1 + f2 * f2 + f3 * f3;
#pragma unroll
  for (int m = 32; m; m >>= 1) s += __shfl_xor(s, m, 64);
  float r = 1.0f / sqrtf(s);
  us4v o;
  o[0] = f2b(f0 * r); o[1] = f2b(f1 * r); o[2] = f2b(f2 * r); o[3] = f2b(f3 * r);
  *(us4v*)p = o;
}

// ---------------- K column sumsq -> rsqK[b][n] ----------------
__global__ __launch_bounds__(256) void sumsqK(
    const u16* __restrict__ KV, float* __restrict__ rsqK)
{
  __shared__ float red[8][132];
  int b = blockIdx.x >> 5, nc = blockIdx.x & 31;
  int n0 = nc * 128;
  int t = threadIdx.x;
  int nn = (t & 31) * 4, cg = t >> 5;
  const u16* base = KV + (long)b * 2 * NB;
  float s0 = 0.f, s1 = 0.f, s2 = 0.f, s3 = 0.f;
  for (int st = 0; st < 32; st++) {
    int c = cg + st * 8;
    us4v v = *(const us4v*)(base + (long)c * 4096 + n0 + nn);
    float a = b2f(v[0]), bb = b2f(v[1]), cc = b2f(v[2]), dd = b2f(v[3]);
    s0 = fmaf(a, a, s0); s1 = fmaf(bb, bb, s1);
    s2 = fmaf(cc, cc, s2); s3 = fmaf(dd, dd, s3);
  }
  red[cg][nn] = s0; red[cg][nn + 1] = s1; red[cg][nn + 2] = s2; red[cg][nn + 3] = s3;
  __syncthreads();
  if (t < 128) {
    float s = 0.f;
#pragma unroll
    for (int g = 0; g < 8; g++) s += red[g][t];
    rsqK[b * 4096 + n0 + t] = 1.0f / sqrtf(s);
  }
}

// ---------------- scale K rows by rsqK + ksum; V rows -> vsum ----------------
__global__ __launch_bounds__(256) void scale_sums(
    u16* __restrict__ KV, const float* __restrict__ rsqK,
    float* __restrict__ ksum, float* __restrict__ vsum)
{
  int z = blockIdx.x;
  int isV = z >> 11, rem = z & 2047, b = rem >> 8, c = rem & 255;
  u16* row = KV + (long)b * 2 * NB + (long)isV * NB + (long)c * 4096;
  const float* rq = rsqK + b * 4096;
  int t = threadIdx.x;
  float s = 0.f;
  short8 v0 = *(const short8*)&row[t * 16];
  short8 v1 = *(const short8*)&row[t * 16 + 8];
  if (!isV) {
    short8 o0, o1;
#pragma unroll
    for (int e = 0; e < 8; e++) {
      float a = b2f((u16)v0[e]) * rq[t * 16 + e];
      float bb = b2f((u16)v1[e]) * rq[t * 16 + 8 + e];
      s += a + bb;
      o0[e] = (short)f2b(a); o1[e] = (short)f2b(bb);
    }
    *(short8*)&row[t * 16] = o0;
    *(short8*)&row[t * 16 + 8] = o1;
  } else {
#pragma unroll
    for (int e = 0; e < 8; e++) s += b2f((u16)v0[e]) + b2f((u16)v1[e]);
  }
#pragma unroll
  for (int off = 32; off; off >>= 1) s += __shfl_down(s, off, 64);
  __shared__ float red[4];
  if ((t & 63) == 0) red[t >> 6] = s;
  __syncthreads();
  if (t == 0)
    (isV ? vsum : ksum)[b * 256 + c] = red[0] + red[1] + red[2] + red[3];
}

// ---------------- den[b][n] = 1/(4096 + Qn[n,:].ksum + eps) ----------------
__global__ __launch_bounds__(256) void denom_k(
    const u16* __restrict__ Qt, const float* __restrict__ ksum,
    float* __restrict__ den)
{
  int row = blockIdx.x * 4 + (threadIdx.x >> 6);
  int lane = threadIdx.x & 63;
  int b = row >> 12;
  us4v v = *(const us4v*)(Qt + (long)row * 256 + lane * 4);
  float4 ks = *(const float4*)&ksum[b * 256 + lane * 4];
  float s = b2f(v[0]) * ks.x + b2f(v[1]) * ks.y + b2f(v[2]) * ks.z + b2f(v[3]) * ks.w;
#pragma unroll
  for (int m = 32; m; m >>= 1) s += __shfl_xor(s, m, 64);
  if (lane == 0) den[row] = 1.0f / (4096.0f + s + 1e-6f);
}

// ---------------- conv3x3 as implicit GEMM (m97 structure) ----------------
// out[m][n] = sum_{d,c} W[m][d*256+c] * img[n + delta(d)][c], K = 2304.
// mode 0: out16[b][n][256] = acc + corr[m][n]
// mode 1: out32[b][m][4096] = (acc + cb[m])*x + x
__global__ __launch_bounds__(256) void conv_gemm(
    const u16* __restrict__ inT, const u16* __restrict__ wr,
    const float* __restrict__ cb, const float* __restrict__ xres,
    u16* __restrict__ out16, float* __restrict__ out32, int mode)
{
  __shared__ __align__(16) u16 As[128 * 32];
  __shared__ __align__(16) u16 Bs[128 * 32];
  int b = blockIdx.z;
  int i0 = blockIdx.y * 128;          // m tile
  int n0 = blockIdx.x * 128;          // n tile (2 image rows)
  int t = threadIdx.x, wave = t >> 6, lane = t & 63;
  int wi = (wave >> 1) * 64, wj = (wave & 1) * 64;
  int li = lane & 15, quad = lane >> 4;
  const u16* inb = inT + (long)b * NB;

  // per-thread staging granules (h = 0,1)
  int ch0 = wave * 128 + lane, ch1 = ch0 + 64;
  int r0 = ch0 >> 2, q0 = ch0 & 3;
  int r1 = ch1 >> 2, q1 = ch1 & 3;
  int y0 = (n0 + r0) >> 6, x0 = (n0 + r0) & 63;
  int y1 = (n0 + r1) >> 6, x1 = (n0 + r1) & 63;
  const u16* Ab0 = wr + (long)(i0 + r0) * 2304 + q0 * 8;
  const u16* Ab1 = wr + (long)(i0 + r1) * 2304 + q1 * 8;
  const u16* Bb0 = inb + (long)((y0 << 6) + x0) * 256 + q0 * 8;
  const u16* Bb1 = inb + (long)((y1 << 6) + x1) * 256 + q1 * 8;
  u16* ldsA0 = &As[(wave * 128) * 8];
  u16* ldsA1 = &As[(wave * 128 + 64) * 8];
  u16* ldsB0 = &Bs[(wave * 128) * 8];
  u16* ldsB1 = &Bs[(wave * 128 + 64) * 8];

  f32x4 acc[4][4];
#pragma unroll
  for (int i = 0; i < 4; i++)
#pragma unroll
    for (int j = 0; j < 4; j++) acc[i][j] = (f32x4){0.f, 0.f, 0.f, 0.f};

  const float4 z4 = {0.f, 0.f, 0.f, 0.f};

#pragma unroll 1
  for (int d = 0; d < 9; d++) {
    int dy = d / 3 - 1, dx = d - (d / 3) * 3 - 1;
    long shift = (long)(dy * 64 + dx) * 256;
    bool v0 = (unsigned)(y0 + dy) < 64u && (unsigned)(x0 + dx) < 64u;
    bool v1 = (unsigned)(y1 + dy) < 64u && (unsigned)(x1 + dx) < 64u;
#pragma unroll 1
    for (int kc = 0; kc < 8; kc++) {
      int k0 = d * 256 + kc * 32;
      ASYNC16(Ab0 + k0, ldsA0);
      ASYNC16(Ab1 + k0, ldsA1);
      if (v0) ASYNC16(Bb0 + shift + kc * 32, ldsB0);
      else    *(float4*)&Bs[ch0 * 8] = z4;
      if (v1) ASYNC16(Bb1 + shift + kc * 32, ldsB1);
      else    *(float4*)&Bs[ch1 * 8] = z4;
      __syncthreads();
      short8 af[4], bf[4];
#pragma unroll
      for (int s = 0; s < 4; s++) af[s] = *(const short8*)&As[(wi + s * 16 + li) * 32 + quad * 8];
#pragma unroll
      for (int s = 0; s < 4; s++) bf[s] = *(const short8*)&Bs[(wj + s * 16 + li) * 32 + quad * 8];
#pragma unroll
      for (int si = 0; si < 4; si++)
#pragma unroll
        for (int sj = 0; sj < 4; sj++)
          acc[si][sj] = __builtin_amdgcn_mfma_f32_16x16x32_bf16(af[si], bf[sj], acc[si][sj], 0, 0, 0);
      __syncthreads();
    }
  }

#pragma unroll
  for (int si = 0; si < 4; si++)
#pragma unroll
    for (int sj = 0; sj < 4; sj++) {
      int col = n0 + wj + sj * 16 + li;              // n
#pragma unroll
      for (int r = 0; r < 4; r++) {
        int row = i0 + wi + si * 16 + quad * 4 + r;  // m
        float v = acc[si][sj][r];
        if (mode == 0) {
          v += cb[(long)row * 4096 + col];           // corr field (incl. c1b + rb term)
          out16[(long)b * NB + (long)col * 256 + row] = f2b(v);
        } else {
          v += cb[row];
          long a = (long)b * NB + (long)row * 4096 + col;
          float xv = xres[a];
          out32[a] = fmaf(v, xv, xv);
        }
      }
    }
}

// ---------------- host ----------------
extern "C" void kernel_launch(void* const* d_in, const int* in_sizes, int n_in,
                              void* d_out, int out_size, void* d_ws, size_t ws_size,
                              hipStream_t stream)
{
  const float* x   = (const float*)d_in[0];
  const float* qw  = (const float*)d_in[1];
  const float* qb  = (const float*)d_in[2];
  const float* kw  = (const float*)d_in[3];
  const float* kb  = (const float*)d_in[4];
  const float* vw  = (const float*)d_in[5];
  const float* vb  = (const float*)d_in[6];
  const float* rw  = (const float*)d_in[7];
  const float* rb  = (const float*)d_in[8];
  const float* c1w = (const float*)d_in[9];
  const float* c1b = (const float*)d_in[10];
  const float* c2w = (const float*)d_in[11];
  const float* c2b = (const float*)d_in[12];

  // ws layout (u16 units)
  u16* U     = (u16*)d_ws;
  u16* xT16  = U;                     // 8388608 ; later wvT16
  u16* Qt16  = U + 8388608;           // 8388608 ; later h1T16
  u16* KV16  = U + 16777216;          // 16777216 (K rows 0-255, V rows 256-511 per b)
  u16* wr2   = U + 33554432;          // 589824
  u16* kvT16 = U + 34144256;          // 524288
  float* Fws = (float*)(U + 34668544);
  float* ksum = Fws;                  // 2048
  float* vsum = Fws + 2048;           // 2048

  // d_out scratch (all dead before conv2 writes d_out; conv2 reads NOTHING here)
  char* ob = (char*)d_out;
  float* kvpart = (float*)(ob + 0);           // 16777216 B
  float* den    = (float*)(ob + 16777216);    // 131072
  float* rsqK   = (float*)(ob + 16908288);    // 131072
  float* corr   = (float*)(ob + 17039360);    // 4194304
  u16*   w1p16  = (u16*)(ob + 21233664);      // 1179648
  u16*   wr1    = (u16*)(ob + 22413312);      // 1179648
  float* T      = (float*)(ob + 23592960);    // 36864
  u16*   rwT16  = (u16*)(ob + 23629824);      // 131072
  u16*   qw16   = (u16*)(ob + 23760896);      // 131072
  u16*   kvw16  = (u16*)(ob + 23891968);      // 262144
  float* kvbias = (float*)(ob + 24154112);    // 2048
  float* outF   = (float*)d_out;

  u16* wvT16 = xT16;
  u16* h1T16 = Qt16;

  dim3 blk(256);

  prep1<<<5633, blk, 0, stream>>>(qw, kw, vw, rw, c1w, c2w, kb, vb,
                                  qw16, kvw16, rwT16, wr1, wr2, kvbias);
  prep_T<<<9, blk, 0, stream>>>(c1w, rb, T);
  corr_k<<<4096, blk, 0, stream>>>(T, c1b, corr);
  transposeX<<<dim3(64, 4, 8), blk, 0, stream>>>(x, xT16);

  // w1' = wr1 @ rwT : folds rw into conv1 weights, layout [m][d*256+cv]
  gemm_nt<<<dim3(2, 18, 1), blk, 0, stream>>>(wr1, rwT16, w1p16,
      256, 256, 256, 0L, 0L, 0L, 256L, 1L, 0, nullptr, nullptr);
  // Qt[b][n][ck] = xT @ qw^T + qb
  gemm_nt<<<dim3(2, 32, 8), blk, 0, stream>>>(xT16, qw16, Qt16,
      256, 256, 256, NB, 0L, NB, 256L, 1L, 0, nullptr, qb);
  // KV[b][cq][n] = [kw|vw] @ x + [kb|vb]
  gemm_nt<<<dim3(32, 4, 8), blk, 0, stream>>>(kvw16, xT16, KV16,
      256, 256, 256, 0L, NB, 2 * NB, 4096L, 1L, 0, kvbias, nullptr);

  normQ<<<8192, blk, 0, stream>>>(Qt16);
  sumsqK<<<256, blk, 0, stream>>>(KV16, rsqK);
  scale_sums<<<4096, blk, 0, stream>>>(KV16, rsqK, ksum, vsum);
  denom_k<<<8192, blk, 0, stream>>>(Qt16, ksum, den);

  gemm_kv<<<dim3(2, 2, 64), blk, 0, stream>>>(KV16, kvpart);
  reduce_kv<<<2048, blk, 0, stream>>>(kvpart, kvT16);

  // wvT[b][n][cv] = (Qt @ kv + vsum)*den   (coalesced stores)
  gemm_nt<<<dim3(2, 32, 8), blk, 0, stream>>>(Qt16, kvT16, wvT16,
      256, 256, 256, NB, 65536L, NB, 256L, 1L, 2, vsum, den);

  conv_gemm<<<dim3(32, 2, 8), blk, 0, stream>>>(wvT16, w1p16, corr, nullptr,
                                                h1T16, nullptr, 0);
  conv_gemm<<<dim3(32, 2, 8), blk, 0, stream>>>(h1T16, wr2, c2b, x,
                                                nullptr, outF, 1);
}